// Round 2
// baseline (160.234 us; speedup 1.0000x reference)
//
#include <hip/hip_runtime.h>

// SupConLoss, B=4096 D=256 L=20, T=0.07.
// loss = mean_l [ sum_i loss_vec_il / (B - singles_l) ]
// loss_vec_il = lp_i + m_i - (masked_sum_il/cnt_il)   (cnt>0), 0 otherwise
// lp_i = log(expsum_i * exp(c_i - m_i) + 1e-20), expsum stabilized by c_i = S_ii.
// masked_sum via one-hot factorization: N = Fb @ Wt^T, Wt[100][256] = sum_j F_j onehot(lab_j).

#define B_N 4096
#define D_K 256
#define L_N 20
#define INVT 14.285714285714286f

// ws layout (bytes)
#define FB_OFF   0x000000u  // bf16 [4096][256]            (2 MB)
#define C_OFF    0x200000u  // f32  [4096]   c_i = S_ii
#define CNT_OFF  0x204000u  // int  [20][5]
#define WT_OFF   0x210000u  // f32  [128][256]  (atomic-accumulated, memset to 0)
#define MP_OFF   0x230000u  // f32  [4096][64]  row-max partials (S units)
#define EP_OFF   0x330000u  // f32  [4096][64]  expsum partials (stab c_i, diag excl)
#define NN_OFF   0x430000u  // f32  [4096][128] masked-sum dots (raw dot units)
#define LP_OFF   0x630000u  // f32  [16][20] per-block loss partials
#define SP_OFF   0x630500u  // f32  [16][20] per-block single counts

typedef __bf16 bf16x8 __attribute__((ext_vector_type(8)));
typedef float f32x4 __attribute__((ext_vector_type(4)));

struct __align__(16) U4 { unsigned int x, y, z, w; };

__device__ __forceinline__ unsigned int f2bf(float x) {
  unsigned int u = __float_as_uint(x);
  return (u + 0x7FFFu + ((u >> 16) & 1u)) >> 16;  // RNE
}

// ---------------- prep: cast->bf16 + rowsumsq | label counts | Wt build ----------------
__global__ __launch_bounds__(256) void k_prep(const float* __restrict__ F,
                                              const int* __restrict__ lab,
                                              unsigned char* __restrict__ ws) {
  __shared__ int sc[4][5];
  const int bid = blockIdx.x, t = threadIdx.x;
  if (bid < 1024) {
    // cast F->bf16, c_i = sumsq/T. one wave per row.
    const int w = t >> 6, l = t & 63;
    const int row = bid * 4 + w;
    float4 v = *(const float4*)(F + row * 256 + l * 4);
    float ss = v.x * v.x + v.y * v.y + v.z * v.z + v.w * v.w;
    #pragma unroll
    for (int off = 1; off < 64; off <<= 1) ss += __shfl_xor(ss, off, 64);
    ushort4 pk;
    pk.x = (unsigned short)f2bf(v.x);
    pk.y = (unsigned short)f2bf(v.y);
    pk.z = (unsigned short)f2bf(v.z);
    pk.w = (unsigned short)f2bf(v.w);
    *(ushort4*)(ws + FB_OFF + (row * 256 + l * 4) * 2) = pk;
    if (l == 0) ((float*)(ws + C_OFF))[row] = ss * INVT;
  } else if (bid < 1044) {
    // counts[l][v]
    const int l = bid - 1024;
    int c0 = 0, c1 = 0, c2 = 0, c3 = 0, c4 = 0;
    for (int j = t; j < B_N; j += 256) {
      int v = lab[j * L_N + l];
      c0 += (v == 0); c1 += (v == 1); c2 += (v == 2); c3 += (v == 3); c4 += (v == 4);
    }
    #pragma unroll
    for (int off = 1; off < 64; off <<= 1) {
      c0 += __shfl_xor(c0, off, 64); c1 += __shfl_xor(c1, off, 64);
      c2 += __shfl_xor(c2, off, 64); c3 += __shfl_xor(c3, off, 64);
      c4 += __shfl_xor(c4, off, 64);
    }
    const int w = t >> 6;
    if ((t & 63) == 0) { sc[w][0] = c0; sc[w][1] = c1; sc[w][2] = c2; sc[w][3] = c3; sc[w][4] = c4; }
    __syncthreads();
    if (t < 5) ((int*)(ws + CNT_OFF))[l * 5 + t] = sc[0][t] + sc[1][t] + sc[2][t] + sc[3][t];
  } else {
    // Wt[5l+v][d] += F[j][d] over j-chunk (atomic fp32)
    const int idx = bid - 1044;
    const int l = idx >> 4, chunk = idx & 15;
    const int d = t;
    float a0 = 0, a1 = 0, a2 = 0, a3 = 0, a4 = 0;
    const int j0 = chunk * 256;
    for (int j = j0; j < j0 + 256; ++j) {
      int v = lab[j * L_N + l];
      float x = F[j * 256 + d];
      a0 += (v == 0) ? x : 0.f;
      a1 += (v == 1) ? x : 0.f;
      a2 += (v == 2) ? x : 0.f;
      a3 += (v == 3) ? x : 0.f;
      a4 += (v == 4) ? x : 0.f;
    }
    float* Wt = (float*)(ws + WT_OFF);
    atomicAdd(Wt + (l * 5 + 0) * 256 + d, a0);
    atomicAdd(Wt + (l * 5 + 1) * 256 + d, a1);
    atomicAdd(Wt + (l * 5 + 2) * 256 + d, a2);
    atomicAdd(Wt + (l * 5 + 3) * 256 + d, a3);
    atomicAdd(Wt + (l * 5 + 4) * 256 + d, a4);
  }
}

// ---------------- main: fused F@F^T row-reduce GEMM (blocks 0..255) + N = Fb@Wt^T (blocks 256..263) --
__global__ __launch_bounds__(512, 2) void k_main(unsigned char* __restrict__ ws) {
  __shared__ unsigned char smem[65536];  // B-panel: [128 rows][256 k] bf16, XOR-swizzled
  const int bid = blockIdx.x, t = threadIdx.x;
  const int w = t >> 6, l = t & 63;
  const int lr = l & 15, lg = l >> 4;
  const unsigned char* fbB = ws + FB_OFF;
  const bool isN = (bid >= 256);
  int rowbase, colb;
  if (!isN) {
    const int bm = bid & 7, bn = bid >> 3;
    rowbase = bm * 512 + w * 64;
    colb = bn * 128;
    // stage Fb rows [colb..colb+128) (cols of C) into swizzled LDS
    const int srow = t >> 2, q = t & 3;
    const unsigned char* src = fbB + (colb + srow) * 512 + q * 128;
    #pragma unroll
    for (int i = 0; i < 8; ++i) {
      U4 v = *(const U4*)(src + i * 16);
      const int kb = q * 128 + i * 16;
      *(U4*)(smem + srow * 512 + (kb ^ ((srow & 7) << 4))) = v;
    }
  } else {
    rowbase = (bid - 256) * 512 + w * 64;
    colb = -(1 << 20);  // never matches a row
    // stage Wt (f32) -> bf16 swizzled LDS
    const float* Wt = (const float*)(ws + WT_OFF);
    for (int s = 0; s < 8; ++s) {
      const int rid = t + s * 512;
      const int srow = rid >> 5, k0 = (rid & 31) * 8;
      float4 f0 = *(const float4*)(Wt + srow * 256 + k0);
      float4 f1 = *(const float4*)(Wt + srow * 256 + k0 + 4);
      U4 pk;
      pk.x = f2bf(f0.x) | (f2bf(f0.y) << 16);
      pk.y = f2bf(f0.z) | (f2bf(f0.w) << 16);
      pk.z = f2bf(f1.x) | (f2bf(f1.y) << 16);
      pk.w = f2bf(f1.z) | (f2bf(f1.w) << 16);
      *(U4*)(smem + srow * 512 + ((k0 * 2) ^ ((srow & 7) << 4))) = pk;
    }
  }
  // A-fragments: 64 rows/wave, all K=256 in registers (32 frags = 128 VGPR)
  bf16x8 afr[4][8];
  #pragma unroll
  for (int mi = 0; mi < 4; ++mi)
    #pragma unroll
    for (int kk = 0; kk < 8; ++kk) {
      U4 va = *(const U4*)(fbB + (rowbase + mi * 16 + lr) * 512 + kk * 64 + lg * 16);
      afr[mi][kk] = __builtin_bit_cast(bf16x8, va);
    }
  __syncthreads();
  const float* cvec = (const float*)(ws + C_OFF);
  float* MP = (float*)(ws + MP_OFF);
  float* EP = (float*)(ws + EP_OFF);
  float* NN = (float*)(ws + NN_OFF);
  #pragma unroll 1
  for (int tile = 0; tile < 2; ++tile) {
    f32x4 acc[4][4] = {};
    #pragma unroll
    for (int kk = 0; kk < 8; ++kk) {
      bf16x8 bfr[4];
      #pragma unroll
      for (int n = 0; n < 4; ++n) {
        const int brow = tile * 64 + n * 16 + lr;
        const int kb = kk * 64 + lg * 16;
        bfr[n] = __builtin_bit_cast(bf16x8,
            *(const U4*)(smem + brow * 512 + (kb ^ ((brow & 7) << 4))));
      }
      #pragma unroll
      for (int mi = 0; mi < 4; ++mi)
        #pragma unroll
        for (int n = 0; n < 4; ++n)
          acc[mi][n] = __builtin_amdgcn_mfma_f32_16x16x32_bf16(afr[mi][kk], bfr[n], acc[mi][n], 0, 0, 0);
    }
    if (!isN) {
      #pragma unroll
      for (int mi = 0; mi < 4; ++mi) {
        #pragma unroll
        for (int r = 0; r < 4; ++r) {
          const int row = rowbase + mi * 16 + lg * 4 + r;
          const float crow = cvec[row];
          float vm = -3.4e38f, es = 0.f;
          #pragma unroll
          for (int n = 0; n < 4; ++n) {
            const int col = colb + tile * 64 + n * 16 + lr;
            const float v = acc[mi][n][r] * INVT;
            vm = fmaxf(vm, v);
            const float e = __expf(v - crow);
            es += (col == row) ? 0.f : e;  // exclude diagonal from expsum
          }
          #pragma unroll
          for (int off = 1; off < 16; off <<= 1) {
            vm = fmaxf(vm, __shfl_xor(vm, off, 16));
            es += __shfl_xor(es, off, 16);
          }
          if (lr == 0) {
            const int c2 = (colb >> 6) + tile;
            MP[row * 64 + c2] = vm;
            EP[row * 64 + c2] = es;
          }
        }
      }
    } else {
      #pragma unroll
      for (int mi = 0; mi < 4; ++mi)
        #pragma unroll
        for (int n = 0; n < 4; ++n) {
          const int col = tile * 64 + n * 16 + lr;
          #pragma unroll
          for (int r = 0; r < 4; ++r) {
            const int row = rowbase + mi * 16 + lg * 4 + r;
            NN[row * 128 + col] = acc[mi][n][r];
          }
        }
    }
  }
}

// ---------------- per-row loss terms + per-l block partials ----------------
__global__ __launch_bounds__(256) void k_final(const int* __restrict__ lab,
                                               unsigned char* __restrict__ ws) {
  __shared__ float sL[4][20], sS[4][20];
  const int t = threadIdx.x;
  const int i = blockIdx.x * 256 + t;
  const float* MP = (const float*)(ws + MP_OFF);
  const float* EP = (const float*)(ws + EP_OFF);
  const float* NNv = (const float*)(ws + NN_OFF);
  const float* cvec = (const float*)(ws + C_OFF);
  const int* cnts = (const int*)(ws + CNT_OFF);
  float m = -3.4e38f, e = 0.f;
  #pragma unroll
  for (int k = 0; k < 16; ++k) {
    float4 mv = *(const float4*)(MP + i * 64 + k * 4);
    float4 ev = *(const float4*)(EP + i * 64 + k * 4);
    m = fmaxf(m, fmaxf(fmaxf(mv.x, mv.y), fmaxf(mv.z, mv.w)));
    e += ev.x + ev.y + ev.z + ev.w;
  }
  const float ci = cvec[i];
  const float lp = logf(e * __expf(ci - m) + 1e-20f);
  const int w = t >> 6, lane = t & 63;
  for (int ll = 0; ll < 20; ++ll) {
    const int v = lab[i * 20 + ll];
    const int cnt = cnts[ll * 5 + v] - 1;  // exclude self
    float lv = 0.f, sg = 0.f;
    if (cnt > 0) {
      const float me = NNv[i * 128 + ll * 5 + v] * INVT - ci;  // masked sum, excl self, S units
      const float ss = me - (float)cnt * m;
      lv = lp - ss / (float)cnt;
    } else {
      sg = 1.f;
    }
    #pragma unroll
    for (int off = 1; off < 64; off <<= 1) {
      lv += __shfl_xor(lv, off, 64);
      sg += __shfl_xor(sg, off, 64);
    }
    if (lane == 0) { sL[w][ll] = lv; sS[w][ll] = sg; }
  }
  __syncthreads();
  if (t < 20) {
    ((float*)(ws + LP_OFF))[blockIdx.x * 20 + t] = sL[0][t] + sL[1][t] + sL[2][t] + sL[3][t];
    ((float*)(ws + SP_OFF))[blockIdx.x * 20 + t] = sS[0][t] + sS[1][t] + sS[2][t] + sS[3][t];
  }
}

// ---------------- final scalar ----------------
__global__ void k_out(unsigned char* __restrict__ ws, float* __restrict__ out) {
  const int t = threadIdx.x;  // 64
  float v = 0.f;
  if (t < 20) {
    const float* LPp = (const float*)(ws + LP_OFF);
    const float* SPp = (const float*)(ws + SP_OFF);
    float Ls = 0.f, Ss = 0.f;
    for (int b = 0; b < 16; ++b) { Ls += LPp[b * 20 + t]; Ss += SPp[b * 20 + t]; }
    v = Ls / (4096.f - Ss);
  }
  #pragma unroll
  for (int off = 1; off < 64; off <<= 1) v += __shfl_xor(v, off, 64);
  if (t == 0) out[0] = v * 0.05f;
}

extern "C" void kernel_launch(void* const* d_in, const int* in_sizes, int n_in,
                              void* d_out, int out_size, void* d_ws, size_t ws_size,
                              hipStream_t stream) {
  const float* F = (const float*)d_in[0];
  const int* lab = (const int*)d_in[1];
  unsigned char* ws = (unsigned char*)d_ws;
  float* out = (float*)d_out;
  hipMemsetAsync(ws + WT_OFF, 0, 128 * 256 * 4, stream);   // zero Wt accumulator
  k_prep<<<1364, 256, 0, stream>>>(F, lab, ws);            // 1024 cast + 20 counts + 320 Wt
  k_main<<<264, 512, 0, stream>>>(ws);                     // 256 F@F^T blocks + 8 N blocks
  k_final<<<16, 256, 0, stream>>>(lab, ws);
  k_out<<<1, 64, 0, stream>>>(ws, out);
}